// Round 7
// baseline (343.824 us; speedup 1.0000x reference)
//
#include <hip/hip_runtime.h>
#include <hip/hip_bf16.h>
#include <stdint.h>

// MultiHeadAttention: B=8, S=1024, D=1024, H=16, DH=64. fp32 in/out (auto-detects bf16).
// Round-7: LDS-read-throughput is the binding resource (b128 ~85 B/cyc/CU).
//  - qkv: 256x128 tile, 2x2 waves (wave=128m x 64n) -> 42.7 FLOP per LDS byte
//  - attn: 2-wave blocks, 64 q-rows/wave; P-tile in chunk-swizzled layout
//    (conflict-free b128 reads; pitch-72 layout had 8-way read conflicts)
//  - out_gemm: 2x2 wave split; prep kernels fused into one dispatch
// ws layout A (>=74MB): WT@0(6) WoT@6(2) bits@8(1) bc@9 Xb@10(16,reused as ctx) Q@26 K@42 Vt@58
// ws layout B (<74MB):  no Xb; ctx in d_out; Fo over Q; emit kernel. peak 58MB

typedef __attribute__((ext_vector_type(8))) short short8;
typedef __attribute__((ext_vector_type(4))) float floatx4;

__device__ __forceinline__ int swz(int r, int kc) { return r * 8 + (kc ^ (r & 7)); }
__device__ __forceinline__ short8 as_frag(uint4 u) { return __builtin_bit_cast(short8, u); }
__device__ __forceinline__ floatx4 mfma16(short8 a, short8 b, floatx4 c) {
    return __builtin_amdgcn_mfma_f32_16x16x32_bf16(a, b, c, 0, 0, 0);
}
__device__ __forceinline__ unsigned short f2bu(float f) {
    return __builtin_bit_cast(unsigned short, __float2bfloat16(f));
}
__device__ __forceinline__ short f2b(float f) {
    return __builtin_bit_cast(short, __float2bfloat16(f));
}
__device__ __forceinline__ float b2f(short s) {
    return __bfloat162float(__builtin_bit_cast(__hip_bfloat16, s));
}
// async global->LDS DMA, 16B per lane; lds dest = wave-uniform base + lane*16
__device__ __forceinline__ void dma16(const void* g, void* l) {
    __builtin_amdgcn_global_load_lds(
        (const __attribute__((address_space(1))) uint32_t*)g,
        (__attribute__((address_space(3))) uint32_t*)l, 16, 0, 0);
}
__device__ __forceinline__ uint2 pack4(float a, float b, float c, float d) {
    uint2 p;
    p.x = (unsigned)f2bu(a) | ((unsigned)f2bu(b) << 16);
    p.y = (unsigned)f2bu(c) | ((unsigned)f2bu(d) << 16);
    return p;
}

// Runtime dtype detection: bf16 data has sane exponents in the LOW halves of
// 32-bit words; fp32 data has uniform mantissa bits there.
__device__ __forceinline__ void detect_mode(const unsigned* Xw, int* s_is32) {
    if (threadIdx.x < 64) {
        unsigned lo = Xw[threadIdx.x] & 0xFFFFu;
        unsigned e = (lo >> 7) & 0xFFu;
        unsigned long long bal = __ballot(e >= 88u && e <= 150u);
        if (threadIdx.x == 0) *s_is32 = (bal != ~0ull) ? 1 : 0;
    }
    __syncthreads();
}

__device__ __forceinline__ float load_elt(const void* p, size_t idx, int is32) {
    return is32 ? ((const float*)p)[idx]
                : __bfloat162float(((const __hip_bfloat16*)p)[idx]);
}

// ---------------------------------------------------------------- fused prep
// blocks [0,1024): weight transpose; [1024]: biases; [1025,1537): mask pack;
// [1537,3585): X convert. All independent.
__global__ __launch_bounds__(256) void prep_all(
    const void* __restrict__ Wq, const void* __restrict__ Wk,
    const void* __restrict__ Wv, const void* __restrict__ Wo,
    const void* __restrict__ bq, const void* __restrict__ bk,
    const void* __restrict__ bv, const void* __restrict__ bo,
    const void* __restrict__ mask_raw, const void* __restrict__ X,
    __hip_bfloat16* __restrict__ WT, __hip_bfloat16* __restrict__ WoT,
    __hip_bfloat16* __restrict__ bc, unsigned long long* __restrict__ bits64,
    __hip_bfloat16* __restrict__ Xb, int do_x)
{
    __shared__ __hip_bfloat16 T[64][72];
    __shared__ int s_is32;
    int blk = blockIdx.x;
    int tid = threadIdx.x;
    const unsigned* Xw = (const unsigned*)X;

    if (blk < 1024) {                           // ---- weight transpose
        detect_mode(Xw, &s_is32);
        const void* src; size_t src_off;
        __hip_bfloat16* dst;
        int src_ld, dst_ld;
        if (blk < 768) {                        // Wq/Wk/Wv: [h][d][e] -> WT[(p,h,e)][d]
            int p = blk >> 8;
            int rem = blk & 255;
            int h = rem >> 4, dt = rem & 15;
            src = (p == 0) ? Wq : (p == 1) ? Wk : Wv;
            src_off = ((size_t)h * 1024 + (size_t)dt * 64) * 64;
            dst = WT + (((size_t)p * 16 + h) * 64) * 1024 + dt * 64;
            src_ld = 64; dst_ld = 1024;
        } else {                                // Wo: [k][n] -> WoT[n][k]
            int t = blk - 768;
            int kt = t >> 4, nt = t & 15;
            src = Wo; src_off = (size_t)kt * 64 * 1024 + nt * 64;
            dst = WoT + (size_t)nt * 64 * 1024 + kt * 64;
            src_ld = 1024; dst_ld = 1024;
        }
        #pragma unroll
        for (int i = 0; i < 16; i++) {
            int idx = tid + i * 256;
            int r = idx >> 6, c = idx & 63;
            T[c][r] = __float2bfloat16(load_elt(src, src_off + (size_t)r * src_ld + c, s_is32));
        }
        __syncthreads();
        #pragma unroll
        for (int i = 0; i < 16; i++) {
            int idx = tid + i * 256;
            int r = idx >> 6, c = idx & 63;
            dst[(size_t)r * dst_ld + c] = T[r][c];
        }
    } else if (blk == 1024) {                   // ---- biases
        detect_mode(Xw, &s_is32);
        #pragma unroll
        for (int i = 0; i < 16; i++) {
            int idx = tid + i * 256;
            int which = idx >> 10, j = idx & 1023;
            const void* src = (which == 0) ? bq : (which == 1) ? bk : (which == 2) ? bv : bo;
            bc[idx] = __float2bfloat16(load_elt(src, j, s_is32));
        }
    } else if (blk < 1537) {                    // ---- mask pack (512 blocks)
        int blkL = blk - 1025;
        const int* mi = (const int*)mask_raw;
        const unsigned char* mb = (const unsigned char*)mask_raw;
        int lane = tid & 63;
        bool ok = true;
        #pragma unroll
        for (int i = 0; i < 4; i++) {
            unsigned v = (unsigned)mi[lane * 4 + i];
            if (v > 1u) ok = false;
        }
        bool is_i32 = (__ballot(ok) == ~0ull);
        int gw = (blkL * 256 + tid) >> 6;
        const int NW = 512 * 4;
        const int NWORDS = (8 * 1024 * 1024) / 64;
        if (is_i32) {
            for (int i = gw; i < NWORDS; i += NW) {
                int mv = mi[(size_t)i * 64 + lane];
                unsigned long long bal = __ballot(mv != 0);
                if (lane == 0) bits64[i] = bal;
            }
        } else {
            for (int i = gw; i < NWORDS; i += NW) {
                int mv = mb[(size_t)i * 64 + lane];
                unsigned long long bal = __ballot(mv != 0);
                if (lane == 0) bits64[i] = bal;
            }
        }
    } else if (do_x) {                          // ---- X convert (2048 blocks)
        detect_mode(Xw, &s_is32);
        int blkL = blk - 1537;
        size_t g = ((size_t)blkL * 256 + tid) * 16;
        if (s_is32) {
            const float* Xf = (const float*)X;
            #pragma unroll
            for (int half = 0; half < 2; half++) {
                float4 f0 = *(const float4*)(Xf + g + half * 8);
                float4 f1 = *(const float4*)(Xf + g + half * 8 + 4);
                short8 s;
                s[0] = f2b(f0.x); s[1] = f2b(f0.y); s[2] = f2b(f0.z); s[3] = f2b(f0.w);
                s[4] = f2b(f1.x); s[5] = f2b(f1.y); s[6] = f2b(f1.z); s[7] = f2b(f1.w);
                *(uint4*)(Xb + g + half * 8) = __builtin_bit_cast(uint4, s);
            }
        } else {
            const uint4* Xu = (const uint4*)X;
            *(uint4*)(Xb + g)     = Xu[g / 8];
            *(uint4*)(Xb + g + 8) = Xu[g / 8 + 1];
        }
    }
}

// ---------------------------------------------------------------- QKV GEMM (DMA)
// C[8192 m, 3072 n] = Xb @ WT^T. 256x128 tiles, grid (32 m, 24 n).
// 2x2 wave grid: wave (mw,nw) covers 128m x 64n -> 24 b128 reads / 64 MFMA per iter.
__global__ __launch_bounds__(256, 2) void qkv_gemm_dma(
    const __hip_bfloat16* __restrict__ Xb,   // [8192][1024] bf16
    const __hip_bfloat16* __restrict__ WT,   // [3072 n][1024 k]
    const __hip_bfloat16* __restrict__ bc,   // [4][1024]
    __hip_bfloat16* __restrict__ Q,
    __hip_bfloat16* __restrict__ Ko,
    __hip_bfloat16* __restrict__ Vt)
{
    __shared__ uint4 AsU[256 * 8];   // 32 KB
    __shared__ uint4 BsU[128 * 8];   // 16 KB
    int tid = threadIdx.x, lane = tid & 63, wave = tid >> 6;
    int quad = lane >> 4, ln = lane & 15;
    int mw = wave & 1, nw = wave >> 1;
    int m0 = blockIdx.x * 256;
    int n0 = blockIdx.y * 128;
    const __hip_bfloat16* Wp = WT + (size_t)n0 * 1024;

    floatx4 acc[8][4];
    #pragma unroll
    for (int i = 0; i < 8; i++)
        #pragma unroll
        for (int j = 0; j < 4; j++) acc[i][j] = (floatx4){0.f, 0.f, 0.f, 0.f};

    for (int k0 = 0; k0 < 1024; k0 += 64) {
        #pragma unroll
        for (int i = 0; i < 8; i++) {          // A: 2048 chunks
            int r = wave * 64 + i * 8 + (lane >> 3);
            int kc = (lane & 7) ^ (r & 7);
            char* lds = (char*)AsU + (size_t)(wave * 512 + i * 64) * 16;
            dma16(Xb + (size_t)(m0 + r) * 1024 + k0 + kc * 8, lds);
        }
        #pragma unroll
        for (int i = 0; i < 4; i++) {          // B: 1024 chunks
            int r = wave * 32 + i * 8 + (lane >> 3);
            int kc = (lane & 7) ^ (r & 7);
            char* lds = (char*)BsU + (size_t)(wave * 256 + i * 64) * 16;
            dma16(Wp + (size_t)r * 1024 + k0 + kc * 8, lds);
        }
        __syncthreads();
        #pragma unroll
        for (int kk = 0; kk < 2; kk++) {
            short8 af[8], bf[4];
            #pragma unroll
            for (int mi = 0; mi < 8; mi++)
                af[mi] = as_frag(AsU[swz(mw * 128 + mi * 16 + ln, kk * 4 + quad)]);
            #pragma unroll
            for (int ni = 0; ni < 4; ni++)
                bf[ni] = as_frag(BsU[swz(nw * 64 + ni * 16 + ln, kk * 4 + quad)]);
            #pragma unroll
            for (int mi = 0; mi < 8; mi++)
                #pragma unroll
                for (int ni = 0; ni < 4; ni++)
                    acc[mi][ni] = mfma16(af[mi], bf[ni], acc[mi][ni]);
        }
        __syncthreads();
    }

    int b = m0 >> 10;
    int s0 = m0 & 1023;
    int proj = n0 >> 10;                     // uniform per block
    if (proj == 2) {
        #pragma unroll
        for (int ni = 0; ni < 4; ni++) {
            int n = n0 + nw * 64 + ni * 16 + ln;
            int h = (n >> 6) & 15, e = n & 63;
            float bval = __bfloat162float(bc[2 * 1024 + (n & 1023)]);
            #pragma unroll
            for (int mi = 0; mi < 8; mi++) {
                int sb = s0 + mw * 128 + mi * 16 + quad * 4;
                uint2 pk = pack4(acc[mi][ni][0] + bval, acc[mi][ni][1] + bval,
                                 acc[mi][ni][2] + bval, acc[mi][ni][3] + bval);
                *(uint2*)(Vt + (((size_t)b * 16 + h) * 64 + e) * 1024 + sb) = pk;
            }
        }
    } else {
        __hip_bfloat16* P = (proj == 0) ? Q : Ko;
        #pragma unroll
        for (int ni = 0; ni < 4; ni++) {
            int n = n0 + nw * 64 + ni * 16 + ln;
            int h = (n >> 6) & 15, e = n & 63;
            float bval = __bfloat162float(bc[proj * 1024 + (n & 1023)]);
            #pragma unroll
            for (int mi = 0; mi < 8; mi++) {
                #pragma unroll
                for (int r = 0; r < 4; r++) {
                    int s = s0 + mw * 128 + mi * 16 + quad * 4 + r;
                    P[(((size_t)b * 16 + h) * 1024 + s) * 64 + e] =
                        __float2bfloat16(acc[mi][ni][r] + bval);
                }
            }
        }
    }
}

// ---------------------------------------------------------------- QKV GEMM (fallback, raw X)
__global__ __launch_bounds__(256) void qkv_gemm2(
    const void* __restrict__ Xsrc,
    const __hip_bfloat16* __restrict__ WT,
    const __hip_bfloat16* __restrict__ bc,
    __hip_bfloat16* __restrict__ Q,
    __hip_bfloat16* __restrict__ Ko,
    __hip_bfloat16* __restrict__ Vt)
{
    __shared__ int s_is32;
    detect_mode((const unsigned*)Xsrc, &s_is32);
    __shared__ uint4 AsU[128 * 8];
    __shared__ uint4 BsU[128 * 8];
    int tid = threadIdx.x, lane = tid & 63, wave = tid >> 6;
    int quad = lane >> 4, ln = lane & 15;
    int m0 = blockIdx.x * 128;
    int n0 = blockIdx.y * 128;
    const __hip_bfloat16* Wp = WT + (size_t)n0 * 1024;
    const float* Xf = (const float*)Xsrc;
    const __hip_bfloat16* Xh = (const __hip_bfloat16*)Xsrc;

    floatx4 acc[2][8];
    #pragma unroll
    for (int i = 0; i < 2; i++)
        #pragma unroll
        for (int j = 0; j < 8; j++) acc[i][j] = (floatx4){0.f, 0.f, 0.f, 0.f};

    for (int k0 = 0; k0 < 1024; k0 += 64) {
        if (s_is32) {
            #pragma unroll
            for (int i = 0; i < 4; i++) {
                int id = tid + i * 256;
                int r = id >> 3, kc = id & 7;
                size_t off = (size_t)(m0 + r) * 1024 + k0 + kc * 8;
                float4 f0 = *(const float4*)(Xf + off);
                float4 f1 = *(const float4*)(Xf + off + 4);
                short8 s;
                s[0] = f2b(f0.x); s[1] = f2b(f0.y); s[2] = f2b(f0.z); s[3] = f2b(f0.w);
                s[4] = f2b(f1.x); s[5] = f2b(f1.y); s[6] = f2b(f1.z); s[7] = f2b(f1.w);
                AsU[swz(r, kc)] = __builtin_bit_cast(uint4, s);
            }
        } else {
            #pragma unroll
            for (int i = 0; i < 4; i++) {
                int id = tid + i * 256;
                int r = id >> 3, kc = id & 7;
                AsU[swz(r, kc)] = *(const uint4*)(Xh + (size_t)(m0 + r) * 1024 + k0 + kc * 8);
            }
        }
        #pragma unroll
        for (int i = 0; i < 4; i++) {
            int id = tid + i * 256;
            int r = id >> 3, kc = id & 7;
            BsU[swz(r, kc)] = *(const uint4*)(Wp + (size_t)r * 1024 + k0 + kc * 8);
        }
        __syncthreads();
        #pragma unroll
        for (int kk = 0; kk < 2; kk++) {
            short8 a0 = as_frag(AsU[swz(wave * 32 + ln, kk * 4 + quad)]);
            short8 a1 = as_frag(AsU[swz(wave * 32 + 16 + ln, kk * 4 + quad)]);
            #pragma unroll
            for (int nt = 0; nt < 8; nt++) {
                short8 bf = as_frag(BsU[swz(nt * 16 + ln, kk * 4 + quad)]);
                acc[0][nt] = mfma16(a0, bf, acc[0][nt]);
                acc[1][nt] = mfma16(a1, bf, acc[1][nt]);
            }
        }
        __syncthreads();
    }

    int b = m0 >> 10;
    int s0 = m0 & 1023;
    #pragma unroll
    for (int nt = 0; nt < 8; nt++) {
        int n = n0 + nt * 16 + ln;
        int proj = n >> 10, h = (n >> 6) & 15, e = n & 63;
        float bval = __bfloat162float(bc[proj * 1024 + (n & 1023)]);
        #pragma unroll
        for (int mt = 0; mt < 2; mt++) {
            #pragma unroll
            for (int r = 0; r < 4; r++) {
                int s = s0 + wave * 32 + mt * 16 + quad * 4 + r;
                float v = acc[mt][nt][r] + bval;
                if (proj == 2) {
                    Vt[(((size_t)b * 16 + h) * 64 + e) * 1024 + s] = __float2bfloat16(v);
                } else {
                    __hip_bfloat16* P = (proj == 0) ? Q : Ko;
                    P[(((size_t)b * 16 + h) * 1024 + s) * 64 + e] = __float2bfloat16(v);
                }
            }
        }
    }
}

// ---------------------------------------------------------------- attention
// grid (128, 8): x = bh (XCD-colocated), y = 128-row Q tile. 2 waves x 64 q-rows.
// Operand-swapped: S^T = K Q^T, O^T = V^T P^T. P stored chunk-swizzled (pitch 64)
// -> conflict-free b128 B-frag reads.
__global__ __launch_bounds__(128) void attn(
    const __hip_bfloat16* __restrict__ Q,
    const __hip_bfloat16* __restrict__ K,
    const __hip_bfloat16* __restrict__ Vt,
    const unsigned long long* __restrict__ bits,  // [8][1024][16]
    __hip_bfloat16* __restrict__ ctx)             // [8][1024][1024]
{
    __shared__ uint4 QsU[128 * 8];                // 16 KB, resident
    __shared__ uint4 KsU[64 * 8];                 // 8 KB
    __shared__ uint4 VsU[64 * 8];                 // 8 KB
    __shared__ uint4 PsU[2 * 64 * 8];             // per-wave P[q][t], swizzled (16 KB)
    __shared__ unsigned long long Ms[128];

    int tid = threadIdx.x, lane = tid & 63, w = tid >> 6;   // w in {0,1}
    int quad = lane >> 4, ln = lane & 15;
    int bh = blockIdx.x;
    int q0 = blockIdx.y * 128;
    int b = bh >> 4, h = bh & 15;
    const __hip_bfloat16* Qp = Q + (size_t)bh * 1024 * 64;
    const __hip_bfloat16* Kp = K + (size_t)bh * 1024 * 64;
    const __hip_bfloat16* Vp = Vt + (size_t)bh * 64 * 1024;
    const unsigned long long* bp = bits + (size_t)b * 1024 * 16;

    // stage Q tile via DMA (wave w covers rows w*64..w*64+64)
    #pragma unroll
    for (int i = 0; i < 8; i++) {
        int r = w * 64 + i * 8 + (lane >> 3);
        int kc = (lane & 7) ^ (r & 7);
        char* lds = (char*)QsU + (size_t)(w * 512 + i * 64) * 16;
        dma16(Qp + (size_t)(q0 + r) * 64 + kc * 8, lds);
    }
    __syncthreads();
    // Q as B-operand: qf[g][kk], lane's q = w*64 + g*16 + ln
    short8 qf[4][2];
    #pragma unroll
    for (int g = 0; g < 4; g++)
        #pragma unroll
        for (int kk = 0; kk < 2; kk++)
            qf[g][kk] = as_frag(QsU[swz(w * 64 + g * 16 + ln, kk * 4 + quad)]);

    floatx4 acc_o[4][4];                          // [qg][e-tile]
    #pragma unroll
    for (int g = 0; g < 4; g++)
        #pragma unroll
        for (int i = 0; i < 4; i++) acc_o[g][i] = (floatx4){0.f, 0.f, 0.f, 0.f};
    float lsum[4] = {0.f, 0.f, 0.f, 0.f};
    const float scale = 0.03125f;                 // 1/sqrt(1024)
    __hip_bfloat16* Pw = (__hip_bfloat16*)&PsU[w * 512];

    for (int t0 = 0; t0 < 1024; t0 += 64) {
        __syncthreads();                          // prior-iter K/V/Ms reads done
        #pragma unroll
        for (int i = 0; i < 4; i++) {             // K + V tiles: 512 chunks each
            int r = w * 32 + i * 8 + (lane >> 3);
            int kc = (lane & 7) ^ (r & 7);
            char* ldsK = (char*)KsU + (size_t)(w * 256 + i * 64) * 16;
            char* ldsV = (char*)VsU + (size_t)(w * 256 + i * 64) * 16;
            dma16(Kp + (size_t)(t0 + r) * 64 + kc * 8, ldsK);
            dma16(Vp + (size_t)r * 1024 + t0 + kc * 8, ldsV);
        }
        Ms[tid] = bp[(size_t)(q0 + tid) * 16 + (t0 >> 6)];
        __syncthreads();

        // S^T = K Q^T: K as A (m=t), Q as B (n=q). K-frags shared across 4 q-groups.
        floatx4 st[4][4];
        #pragma unroll
        for (int g = 0; g < 4; g++)
            #pragma unroll
            for (int i = 0; i < 4; i++) st[g][i] = (floatx4){0.f, 0.f, 0.f, 0.f};
        #pragma unroll
        for (int kk = 0; kk < 2; kk++) {
            #pragma unroll
            for (int tt = 0; tt < 4; tt++) {
                short8 kf = as_frag(KsU[swz(tt * 16 + ln, kk * 4 + quad)]);
                #pragma unroll
                for (int g = 0; g < 4; g++)
                    st[g][tt] = mfma16(kf, qf[g][kk], st[g][tt]);
            }
        }

        // P = masked exp; write into swizzled chunk layout: row=q_loc, col=t
        #pragma unroll
        for (int g = 0; g < 4; g++) {
            int qloc = g * 16 + ln;
            unsigned long long mw = Ms[w * 64 + qloc];
            #pragma unroll
            for (int tt = 0; tt < 4; tt++) {
                unsigned mb = (unsigned)(mw >> (tt * 16 + quad * 4)) & 0xFu;
                float pe0 = (mb & 1u) ? 0.f : __expf(st[g][tt][0] * scale);
                float pe1 = (mb & 2u) ? 0.f : __expf(st[g][tt][1] * scale);
                float pe2 = (mb & 4u) ? 0.f : __expf(st[g][tt][2] * scale);
                float pe3 = (mb & 8u) ? 0.f : __expf(st[g][tt][3] * scale);
                lsum[g] += (pe0 + pe1) + (pe2 + pe3);
                int kc = tt * 2 + (quad >> 1);            // logical chunk of col
                int off = qloc * 64 + (kc ^ (qloc & 7)) * 8 + (quad & 1) * 4;
                *(uint2*)(Pw + off) = pack4(pe0, pe1, pe2, pe3);
            }
        }

        // O^T += V^T P^T: V as A (rows e), P as B (standard swizzled read)
        #pragma unroll
        for (int kk = 0; kk < 2; kk++) {
            short8 pf[4];
            #pragma unroll
            for (int g = 0; g < 4; g++)
                pf[g] = as_frag(PsU[w * 512 + swz(g * 16 + ln, kk * 4 + quad)]);
            #pragma unroll
            for (int et = 0; et < 4; et++) {
                short8 vf = as_frag(VsU[swz(et * 16 + ln, kk * 4 + quad)]);
                #pragma unroll
                for (int g = 0; g < 4; g++)
                    acc_o[g][et] = mfma16(vf, pf[g], acc_o[g][et]);
            }
        }
    }

    // reduce l across quads (each quad summed its t-subset)
    #pragma unroll
    for (int g = 0; g < 4; g++) {
        lsum[g] += __shfl_xor(lsum[g], 16, 64);
        lsum[g] += __shfl_xor(lsum[g], 32, 64);
    }

    // O^T C-layout: col=q=ln, row=e=quad*4+r -> 4 consecutive d per lane: 8B stores
    #pragma unroll
    for (int g = 0; g < 4; g++) {
        float inv = 1.f / fmaxf(lsum[g], 1e-20f);
        int s = q0 + w * 64 + g * 16 + ln;
        __hip_bfloat16* crow = ctx + ((size_t)b * 1024 + s) * 1024 + h * 64 + quad * 4;
        #pragma unroll
        for (int et = 0; et < 4; et++) {
            uint2 pk = pack4(acc_o[g][et][0] * inv, acc_o[g][et][1] * inv,
                             acc_o[g][et][2] * inv, acc_o[g][et][3] * inv);
            *(uint2*)(crow + et * 16) = pk;
        }
    }
}

// ---------------------------------------------------------------- out GEMM (DMA)
// 128x128 tiles, 2x2 waves (wave = 64m x 64n); fused dual-mode output write.
__global__ __launch_bounds__(256) void out_gemm_dma(
    const __hip_bfloat16* __restrict__ Cx,   // ctx [8192,1024]
    const __hip_bfloat16* __restrict__ WoT,  // [1024 n][1024 k]
    const __hip_bfloat16* __restrict__ bc,
    const unsigned* __restrict__ Xw,
    void* __restrict__ dout,
    int direct)
{
    __shared__ int s_is32;
    detect_mode(Xw, &s_is32);
    __shared__ uint4 AsU[128 * 8];
    __shared__ uint4 BsU[128 * 8];
    int tid = threadIdx.x, lane = tid & 63, wave = tid >> 6;
    int quad = lane >> 4, ln = lane & 15;
    int mw = wave & 1, nw = wave >> 1;
    int m0 = blockIdx.x * 128;
    int n0 = blockIdx.y * 128;

    floatx4 acc[4][4];
    #pragma unroll
    for (int i = 0; i < 4; i++)
        #pragma unroll
        for (int j = 0; j < 4; j++) acc[i][j] = (floatx4){0.f, 0.f, 0.f, 0.f};

    for (int k0 = 0; k0 < 1024; k0 += 64) {
        #pragma unroll
        for (int i = 0; i < 4; i++) {
            int r = wave * 32 + i * 8 + (lane >> 3);
            int kc = (lane & 7) ^ (r & 7);
            char* ldsA = (char*)AsU + (size_t)(wave * 256 + i * 64) * 16;
            char* ldsB = (char*)BsU + (size_t)(wave * 256 + i * 64) * 16;
            dma16(Cx + (size_t)(m0 + r) * 1024 + k0 + kc * 8, ldsA);
            dma16(WoT + (size_t)(n0 + r) * 1024 + k0 + kc * 8, ldsB);
        }
        __syncthreads();
        #pragma unroll
        for (int kk = 0; kk < 2; kk++) {
            short8 af[4], bf[4];
            #pragma unroll
            for (int mi = 0; mi < 4; mi++)
                af[mi] = as_frag(AsU[swz(mw * 64 + mi * 16 + ln, kk * 4 + quad)]);
            #pragma unroll
            for (int ni = 0; ni < 4; ni++)
                bf[ni] = as_frag(BsU[swz(nw * 64 + ni * 16 + ln, kk * 4 + quad)]);
            #pragma unroll
            for (int mi = 0; mi < 4; mi++)
                #pragma unroll
                for (int ni = 0; ni < 4; ni++)
                    acc[mi][ni] = mfma16(af[mi], bf[ni], acc[mi][ni]);
        }
        __syncthreads();
    }

    const __hip_bfloat16* bo = bc + 3 * 1024;
    #pragma unroll
    for (int ni = 0; ni < 4; ni++) {
        int n = n0 + nw * 64 + ni * 16 + ln;
        float bval = __bfloat162float(bo[n]);
        #pragma unroll
        for (int mi = 0; mi < 4; mi++) {
            #pragma unroll
            for (int r = 0; r < 4; r++) {
                int m = m0 + mw * 64 + mi * 16 + quad * 4 + r;
                float v = acc[mi][ni][r] + bval;
                if (direct && s_is32) ((float*)dout)[(size_t)m * 1024 + n] = v;
                else ((__hip_bfloat16*)dout)[(size_t)m * 1024 + n] = __float2bfloat16(v);
            }
        }
    }
}

// ---------------------------------------------------------------- emit (fallback)
__global__ __launch_bounds__(256) void emit_out(
    const __hip_bfloat16* __restrict__ Fo, const unsigned* __restrict__ Xw,
    void* __restrict__ dout)
{
    __shared__ int s_is32;
    detect_mode(Xw, &s_is32);
    size_t g = (size_t)blockIdx.x * 256 + threadIdx.x;
    uint4 u = *(const uint4*)(Fo + g * 8);
    if (s_is32) {
        short8 s = __builtin_bit_cast(short8, u);
        float4 f0, f1;
        f0.x = b2f(s[0]); f0.y = b2f(s[1]); f0.z = b2f(s[2]); f0.w = b2f(s[3]);
        f1.x = b2f(s[4]); f1.y = b2f(s[5]); f1.z = b2f(s[6]); f1.w = b2f(s[7]);
        *(float4*)((float*)dout + g * 8) = f0;
        *(float4*)((float*)dout + g * 8 + 4) = f1;
    } else {
        *(uint4*)((__hip_bfloat16*)dout + g * 8) = u;
    }
}

// ---------------------------------------------------------------- launch
extern "C" void kernel_launch(void* const* d_in, const int* in_sizes, int n_in,
                              void* d_out, int out_size, void* d_ws, size_t ws_size,
                              hipStream_t stream) {
    const void* X  = d_in[0];
    const void* mk = d_in[1];
    const void* Wq = d_in[2];
    const void* bq = d_in[3];
    const void* Wk = d_in[4];
    const void* bk = d_in[5];
    const void* Wv = d_in[6];
    const void* bv = d_in[7];
    const void* Wo = d_in[8];
    const void* bo = d_in[9];
    const unsigned* Xw = (const unsigned*)X;

    char* ws = (char*)d_ws;
    __hip_bfloat16*     WT   = (__hip_bfloat16*)(ws);                        // [0, 6 MB)
    __hip_bfloat16*     WoT  = (__hip_bfloat16*)(ws + ((size_t)6 << 20));    // [6, 8 MB)
    unsigned long long* bits = (unsigned long long*)(ws + ((size_t)8 << 20));// [8, 9 MB)
    __hip_bfloat16*     bc   = (__hip_bfloat16*)(ws + ((size_t)9 << 20));    // [9, +8KB)
    __hip_bfloat16*     Xb   = (__hip_bfloat16*)(ws + ((size_t)10 << 20));   // [10, 26 MB)
    __hip_bfloat16*     Qb   = (__hip_bfloat16*)(ws + ((size_t)26 << 20));   // [26, 42 MB)
    __hip_bfloat16*     Kb   = (__hip_bfloat16*)(ws + ((size_t)42 << 20));   // [42, 58 MB)
    __hip_bfloat16*     Vtb  = (__hip_bfloat16*)(ws + ((size_t)58 << 20));   // [58, 74 MB)

    bool bigws = ws_size >= ((size_t)74 << 20);

    hipLaunchKernelGGL(prep_all, dim3(3585), dim3(256), 0, stream,
                       Wq, Wk, Wv, Wo, bq, bk, bv, bo, mk, X,
                       WT, WoT, bc, bits, Xb, bigws ? 1 : 0);

    if (bigws) {
        __hip_bfloat16* Cx = Xb;   // ctx reuses Xb (dead after qkv)
        hipLaunchKernelGGL(qkv_gemm_dma, dim3(32, 24), dim3(256), 0, stream,
                           Xb, WT, bc, Qb, Kb, Vtb);
        hipLaunchKernelGGL(attn, dim3(128, 8), dim3(128), 0, stream,
                           Qb, Kb, Vtb, bits, Cx);
        hipLaunchKernelGGL(out_gemm_dma, dim3(64, 8), dim3(256), 0, stream,
                           Cx, WoT, bc, Xw, d_out, 1);
    } else {
        __hip_bfloat16* Cx = (__hip_bfloat16*)d_out;   // ctx scratch in d_out
        __hip_bfloat16* Fo = Qb;                        // final bf16 over dead Q
        hipLaunchKernelGGL(qkv_gemm2, dim3(64, 24), dim3(256), 0, stream,
                           X, WT, bc, Qb, Kb, Vtb);
        hipLaunchKernelGGL(attn, dim3(128, 8), dim3(128), 0, stream,
                           Qb, Kb, Vtb, bits, Cx);
        hipLaunchKernelGGL(out_gemm_dma, dim3(64, 8), dim3(256), 0, stream,
                           Cx, WoT, bc, Xw, (void*)Fo, 0);
        hipLaunchKernelGGL(emit_out, dim3(4096), dim3(256), 0, stream,
                           Fo, Xw, d_out);
    }
}

// Round 8
// 307.431 us; speedup vs baseline: 1.1184x; 1.1184x over previous
//
#include <hip/hip_runtime.h>
#include <hip/hip_bf16.h>
#include <stdint.h>

// MultiHeadAttention: B=8, S=1024, D=1024, H=16, DH=64. fp32 in/out (auto-detects bf16).
// Round-8: attn occupancy recovery — 4 waves x 32 q-rows (q-tile 128, 1024 blocks),
// Q-frags loaded direct-to-register from global (no Q LDS), P in swizzled chunk
// layout (conflict-free reads). LDS 33 KB -> 4 blocks/CU = 16 waves/CU.
// qkv: 256x128 tile, 2x2 waves (42.7 FLOP/LDS-byte). out: 128x128, 2x2 waves.
// ws layout A (>=74MB): WT@0(6) WoT@6(2) bits@8(1) bc@9 Xb@10(16,reused as ctx) Q@26 K@42 Vt@58
// ws layout B (<74MB):  no Xb; ctx in d_out; Fo over Q; emit kernel. peak 58MB

typedef __attribute__((ext_vector_type(8))) short short8;
typedef __attribute__((ext_vector_type(4))) float floatx4;

__device__ __forceinline__ int swz(int r, int kc) { return r * 8 + (kc ^ (r & 7)); }
__device__ __forceinline__ short8 as_frag(uint4 u) { return __builtin_bit_cast(short8, u); }
__device__ __forceinline__ floatx4 mfma16(short8 a, short8 b, floatx4 c) {
    return __builtin_amdgcn_mfma_f32_16x16x32_bf16(a, b, c, 0, 0, 0);
}
__device__ __forceinline__ unsigned short f2bu(float f) {
    return __builtin_bit_cast(unsigned short, __float2bfloat16(f));
}
__device__ __forceinline__ short f2b(float f) {
    return __builtin_bit_cast(short, __float2bfloat16(f));
}
__device__ __forceinline__ float b2f(short s) {
    return __bfloat162float(__builtin_bit_cast(__hip_bfloat16, s));
}
// async global->LDS DMA, 16B per lane; lds dest = wave-uniform base + lane*16
__device__ __forceinline__ void dma16(const void* g, void* l) {
    __builtin_amdgcn_global_load_lds(
        (const __attribute__((address_space(1))) uint32_t*)g,
        (__attribute__((address_space(3))) uint32_t*)l, 16, 0, 0);
}
__device__ __forceinline__ uint2 pack4(float a, float b, float c, float d) {
    uint2 p;
    p.x = (unsigned)f2bu(a) | ((unsigned)f2bu(b) << 16);
    p.y = (unsigned)f2bu(c) | ((unsigned)f2bu(d) << 16);
    return p;
}

// Runtime dtype detection: bf16 data has sane exponents in the LOW halves of
// 32-bit words; fp32 data has uniform mantissa bits there.
__device__ __forceinline__ void detect_mode(const unsigned* Xw, int* s_is32) {
    if (threadIdx.x < 64) {
        unsigned lo = Xw[threadIdx.x] & 0xFFFFu;
        unsigned e = (lo >> 7) & 0xFFu;
        unsigned long long bal = __ballot(e >= 88u && e <= 150u);
        if (threadIdx.x == 0) *s_is32 = (bal != ~0ull) ? 1 : 0;
    }
    __syncthreads();
}

__device__ __forceinline__ float load_elt(const void* p, size_t idx, int is32) {
    return is32 ? ((const float*)p)[idx]
                : __bfloat162float(((const __hip_bfloat16*)p)[idx]);
}

// ---------------------------------------------------------------- fused prep
// blocks [0,1024): weight transpose; [1024]: biases; [1025,1537): mask pack;
// [1537,3585): X convert. All independent.
__global__ __launch_bounds__(256) void prep_all(
    const void* __restrict__ Wq, const void* __restrict__ Wk,
    const void* __restrict__ Wv, const void* __restrict__ Wo,
    const void* __restrict__ bq, const void* __restrict__ bk,
    const void* __restrict__ bv, const void* __restrict__ bo,
    const void* __restrict__ mask_raw, const void* __restrict__ X,
    __hip_bfloat16* __restrict__ WT, __hip_bfloat16* __restrict__ WoT,
    __hip_bfloat16* __restrict__ bc, unsigned long long* __restrict__ bits64,
    __hip_bfloat16* __restrict__ Xb, int do_x)
{
    __shared__ __hip_bfloat16 T[64][72];
    __shared__ int s_is32;
    int blk = blockIdx.x;
    int tid = threadIdx.x;
    const unsigned* Xw = (const unsigned*)X;

    if (blk < 1024) {                           // ---- weight transpose
        detect_mode(Xw, &s_is32);
        const void* src; size_t src_off;
        __hip_bfloat16* dst;
        int src_ld, dst_ld;
        if (blk < 768) {                        // Wq/Wk/Wv: [h][d][e] -> WT[(p,h,e)][d]
            int p = blk >> 8;
            int rem = blk & 255;
            int h = rem >> 4, dt = rem & 15;
            src = (p == 0) ? Wq : (p == 1) ? Wk : Wv;
            src_off = ((size_t)h * 1024 + (size_t)dt * 64) * 64;
            dst = WT + (((size_t)p * 16 + h) * 64) * 1024 + dt * 64;
            src_ld = 64; dst_ld = 1024;
        } else {                                // Wo: [k][n] -> WoT[n][k]
            int t = blk - 768;
            int kt = t >> 4, nt = t & 15;
            src = Wo; src_off = (size_t)kt * 64 * 1024 + nt * 64;
            dst = WoT + (size_t)nt * 64 * 1024 + kt * 64;
            src_ld = 1024; dst_ld = 1024;
        }
        #pragma unroll
        for (int i = 0; i < 16; i++) {
            int idx = tid + i * 256;
            int r = idx >> 6, c = idx & 63;
            T[c][r] = __float2bfloat16(load_elt(src, src_off + (size_t)r * src_ld + c, s_is32));
        }
        __syncthreads();
        #pragma unroll
        for (int i = 0; i < 16; i++) {
            int idx = tid + i * 256;
            int r = idx >> 6, c = idx & 63;
            dst[(size_t)r * dst_ld + c] = T[r][c];
        }
    } else if (blk == 1024) {                   // ---- biases
        detect_mode(Xw, &s_is32);
        #pragma unroll
        for (int i = 0; i < 16; i++) {
            int idx = tid + i * 256;
            int which = idx >> 10, j = idx & 1023;
            const void* src = (which == 0) ? bq : (which == 1) ? bk : (which == 2) ? bv : bo;
            bc[idx] = __float2bfloat16(load_elt(src, j, s_is32));
        }
    } else if (blk < 1537) {                    // ---- mask pack (512 blocks)
        int blkL = blk - 1025;
        const int* mi = (const int*)mask_raw;
        const unsigned char* mb = (const unsigned char*)mask_raw;
        int lane = tid & 63;
        bool ok = true;
        #pragma unroll
        for (int i = 0; i < 4; i++) {
            unsigned v = (unsigned)mi[lane * 4 + i];
            if (v > 1u) ok = false;
        }
        bool is_i32 = (__ballot(ok) == ~0ull);
        int gw = (blkL * 256 + tid) >> 6;
        const int NW = 512 * 4;
        const int NWORDS = (8 * 1024 * 1024) / 64;
        if (is_i32) {
            for (int i = gw; i < NWORDS; i += NW) {
                int mv = mi[(size_t)i * 64 + lane];
                unsigned long long bal = __ballot(mv != 0);
                if (lane == 0) bits64[i] = bal;
            }
        } else {
            for (int i = gw; i < NWORDS; i += NW) {
                int mv = mb[(size_t)i * 64 + lane];
                unsigned long long bal = __ballot(mv != 0);
                if (lane == 0) bits64[i] = bal;
            }
        }
    } else if (do_x) {                          // ---- X convert (2048 blocks)
        detect_mode(Xw, &s_is32);
        int blkL = blk - 1537;
        size_t g = ((size_t)blkL * 256 + tid) * 16;
        if (s_is32) {
            const float* Xf = (const float*)X;
            #pragma unroll
            for (int half = 0; half < 2; half++) {
                float4 f0 = *(const float4*)(Xf + g + half * 8);
                float4 f1 = *(const float4*)(Xf + g + half * 8 + 4);
                short8 s;
                s[0] = f2b(f0.x); s[1] = f2b(f0.y); s[2] = f2b(f0.z); s[3] = f2b(f0.w);
                s[4] = f2b(f1.x); s[5] = f2b(f1.y); s[6] = f2b(f1.z); s[7] = f2b(f1.w);
                *(uint4*)(Xb + g + half * 8) = __builtin_bit_cast(uint4, s);
            }
        } else {
            const uint4* Xu = (const uint4*)X;
            *(uint4*)(Xb + g)     = Xu[g / 8];
            *(uint4*)(Xb + g + 8) = Xu[g / 8 + 1];
        }
    }
}

// ---------------------------------------------------------------- QKV GEMM (DMA)
// C[8192 m, 3072 n] = Xb @ WT^T. 256x128 tiles, grid (32 m, 24 n).
// 2x2 wave grid: wave (mw,nw) covers 128m x 64n -> 24 b128 reads / 64 MFMA per iter.
__global__ __launch_bounds__(256, 2) void qkv_gemm_dma(
    const __hip_bfloat16* __restrict__ Xb,   // [8192][1024] bf16
    const __hip_bfloat16* __restrict__ WT,   // [3072 n][1024 k]
    const __hip_bfloat16* __restrict__ bc,   // [4][1024]
    __hip_bfloat16* __restrict__ Q,
    __hip_bfloat16* __restrict__ Ko,
    __hip_bfloat16* __restrict__ Vt)
{
    __shared__ uint4 AsU[256 * 8];   // 32 KB
    __shared__ uint4 BsU[128 * 8];   // 16 KB
    int tid = threadIdx.x, lane = tid & 63, wave = tid >> 6;
    int quad = lane >> 4, ln = lane & 15;
    int mw = wave & 1, nw = wave >> 1;
    int m0 = blockIdx.x * 256;
    int n0 = blockIdx.y * 128;
    const __hip_bfloat16* Wp = WT + (size_t)n0 * 1024;

    floatx4 acc[8][4];
    #pragma unroll
    for (int i = 0; i < 8; i++)
        #pragma unroll
        for (int j = 0; j < 4; j++) acc[i][j] = (floatx4){0.f, 0.f, 0.f, 0.f};

    for (int k0 = 0; k0 < 1024; k0 += 64) {
        #pragma unroll
        for (int i = 0; i < 8; i++) {          // A: 2048 chunks
            int r = wave * 64 + i * 8 + (lane >> 3);
            int kc = (lane & 7) ^ (r & 7);
            char* lds = (char*)AsU + (size_t)(wave * 512 + i * 64) * 16;
            dma16(Xb + (size_t)(m0 + r) * 1024 + k0 + kc * 8, lds);
        }
        #pragma unroll
        for (int i = 0; i < 4; i++) {          // B: 1024 chunks
            int r = wave * 32 + i * 8 + (lane >> 3);
            int kc = (lane & 7) ^ (r & 7);
            char* lds = (char*)BsU + (size_t)(wave * 256 + i * 64) * 16;
            dma16(Wp + (size_t)r * 1024 + k0 + kc * 8, lds);
        }
        __syncthreads();
        #pragma unroll
        for (int kk = 0; kk < 2; kk++) {
            short8 af[8], bf[4];
            #pragma unroll
            for (int mi = 0; mi < 8; mi++)
                af[mi] = as_frag(AsU[swz(mw * 128 + mi * 16 + ln, kk * 4 + quad)]);
            #pragma unroll
            for (int ni = 0; ni < 4; ni++)
                bf[ni] = as_frag(BsU[swz(nw * 64 + ni * 16 + ln, kk * 4 + quad)]);
            #pragma unroll
            for (int mi = 0; mi < 8; mi++)
                #pragma unroll
                for (int ni = 0; ni < 4; ni++)
                    acc[mi][ni] = mfma16(af[mi], bf[ni], acc[mi][ni]);
        }
        __syncthreads();
    }

    int b = m0 >> 10;
    int s0 = m0 & 1023;
    int proj = n0 >> 10;                     // uniform per block
    if (proj == 2) {
        #pragma unroll
        for (int ni = 0; ni < 4; ni++) {
            int n = n0 + nw * 64 + ni * 16 + ln;
            int h = (n >> 6) & 15, e = n & 63;
            float bval = __bfloat162float(bc[2 * 1024 + (n & 1023)]);
            #pragma unroll
            for (int mi = 0; mi < 8; mi++) {
                int sb = s0 + mw * 128 + mi * 16 + quad * 4;
                uint2 pk = pack4(acc[mi][ni][0] + bval, acc[mi][ni][1] + bval,
                                 acc[mi][ni][2] + bval, acc[mi][ni][3] + bval);
                *(uint2*)(Vt + (((size_t)b * 16 + h) * 64 + e) * 1024 + sb) = pk;
            }
        }
    } else {
        __hip_bfloat16* P = (proj == 0) ? Q : Ko;
        #pragma unroll
        for (int ni = 0; ni < 4; ni++) {
            int n = n0 + nw * 64 + ni * 16 + ln;
            int h = (n >> 6) & 15, e = n & 63;
            float bval = __bfloat162float(bc[proj * 1024 + (n & 1023)]);
            #pragma unroll
            for (int mi = 0; mi < 8; mi++) {
                #pragma unroll
                for (int r = 0; r < 4; r++) {
                    int s = s0 + mw * 128 + mi * 16 + quad * 4 + r;
                    P[(((size_t)b * 16 + h) * 1024 + s) * 64 + e] =
                        __float2bfloat16(acc[mi][ni][r] + bval);
                }
            }
        }
    }
}

// ---------------------------------------------------------------- QKV GEMM (fallback, raw X)
__global__ __launch_bounds__(256) void qkv_gemm2(
    const void* __restrict__ Xsrc,
    const __hip_bfloat16* __restrict__ WT,
    const __hip_bfloat16* __restrict__ bc,
    __hip_bfloat16* __restrict__ Q,
    __hip_bfloat16* __restrict__ Ko,
    __hip_bfloat16* __restrict__ Vt)
{
    __shared__ int s_is32;
    detect_mode((const unsigned*)Xsrc, &s_is32);
    __shared__ uint4 AsU[128 * 8];
    __shared__ uint4 BsU[128 * 8];
    int tid = threadIdx.x, lane = tid & 63, wave = tid >> 6;
    int quad = lane >> 4, ln = lane & 15;
    int m0 = blockIdx.x * 128;
    int n0 = blockIdx.y * 128;
    const __hip_bfloat16* Wp = WT + (size_t)n0 * 1024;
    const float* Xf = (const float*)Xsrc;
    const __hip_bfloat16* Xh = (const __hip_bfloat16*)Xsrc;

    floatx4 acc[2][8];
    #pragma unroll
    for (int i = 0; i < 2; i++)
        #pragma unroll
        for (int j = 0; j < 8; j++) acc[i][j] = (floatx4){0.f, 0.f, 0.f, 0.f};

    for (int k0 = 0; k0 < 1024; k0 += 64) {
        if (s_is32) {
            #pragma unroll
            for (int i = 0; i < 4; i++) {
                int id = tid + i * 256;
                int r = id >> 3, kc = id & 7;
                size_t off = (size_t)(m0 + r) * 1024 + k0 + kc * 8;
                float4 f0 = *(const float4*)(Xf + off);
                float4 f1 = *(const float4*)(Xf + off + 4);
                short8 s;
                s[0] = f2b(f0.x); s[1] = f2b(f0.y); s[2] = f2b(f0.z); s[3] = f2b(f0.w);
                s[4] = f2b(f1.x); s[5] = f2b(f1.y); s[6] = f2b(f1.z); s[7] = f2b(f1.w);
                AsU[swz(r, kc)] = __builtin_bit_cast(uint4, s);
            }
        } else {
            #pragma unroll
            for (int i = 0; i < 4; i++) {
                int id = tid + i * 256;
                int r = id >> 3, kc = id & 7;
                AsU[swz(r, kc)] = *(const uint4*)(Xh + (size_t)(m0 + r) * 1024 + k0 + kc * 8);
            }
        }
        #pragma unroll
        for (int i = 0; i < 4; i++) {
            int id = tid + i * 256;
            int r = id >> 3, kc = id & 7;
            BsU[swz(r, kc)] = *(const uint4*)(Wp + (size_t)r * 1024 + k0 + kc * 8);
        }
        __syncthreads();
        #pragma unroll
        for (int kk = 0; kk < 2; kk++) {
            short8 a0 = as_frag(AsU[swz(wave * 32 + ln, kk * 4 + quad)]);
            short8 a1 = as_frag(AsU[swz(wave * 32 + 16 + ln, kk * 4 + quad)]);
            #pragma unroll
            for (int nt = 0; nt < 8; nt++) {
                short8 bf = as_frag(BsU[swz(nt * 16 + ln, kk * 4 + quad)]);
                acc[0][nt] = mfma16(a0, bf, acc[0][nt]);
                acc[1][nt] = mfma16(a1, bf, acc[1][nt]);
            }
        }
        __syncthreads();
    }

    int b = m0 >> 10;
    int s0 = m0 & 1023;
    #pragma unroll
    for (int nt = 0; nt < 8; nt++) {
        int n = n0 + nt * 16 + ln;
        int proj = n >> 10, h = (n >> 6) & 15, e = n & 63;
        float bval = __bfloat162float(bc[proj * 1024 + (n & 1023)]);
        #pragma unroll
        for (int mt = 0; mt < 2; mt++) {
            #pragma unroll
            for (int r = 0; r < 4; r++) {
                int s = s0 + wave * 32 + mt * 16 + quad * 4 + r;
                float v = acc[mt][nt][r] + bval;
                if (proj == 2) {
                    Vt[(((size_t)b * 16 + h) * 64 + e) * 1024 + s] = __float2bfloat16(v);
                } else {
                    __hip_bfloat16* P = (proj == 0) ? Q : Ko;
                    P[(((size_t)b * 16 + h) * 1024 + s) * 64 + e] = __float2bfloat16(v);
                }
            }
        }
    }
}

// ---------------------------------------------------------------- attention
// grid (128, 8): x = bh (XCD-colocated), y = 128-row Q tile. 4 waves x 32 q-rows.
// Operand-swapped: S^T = K Q^T, O^T = V^T P^T. Q-frags direct from global (no Q LDS).
// P per-wave, chunk-swizzled -> conflict-free b128 reads. LDS 33 KB -> 4 blocks/CU.
__global__ __launch_bounds__(256, 4) void attn(
    const __hip_bfloat16* __restrict__ Q,
    const __hip_bfloat16* __restrict__ K,
    const __hip_bfloat16* __restrict__ Vt,
    const unsigned long long* __restrict__ bits,  // [8][1024][16]
    __hip_bfloat16* __restrict__ ctx)             // [8][1024][1024]
{
    __shared__ uint4 KsU[64 * 8];                 // 8 KB
    __shared__ uint4 VsU[64 * 8];                 // 8 KB
    __shared__ uint4 PsU[4 * 256];                // 4 waves x 32q x 8 chunks (16 KB)
    __shared__ unsigned long long Ms[128];

    int tid = threadIdx.x, lane = tid & 63, w = tid >> 6;   // w in {0..3}
    int quad = lane >> 4, ln = lane & 15;
    int bh = blockIdx.x;
    int q0 = blockIdx.y * 128;
    int b = bh >> 4, h = bh & 15;
    const __hip_bfloat16* Qp = Q + (size_t)bh * 1024 * 64;
    const __hip_bfloat16* Kp = K + (size_t)bh * 1024 * 64;
    const __hip_bfloat16* Vp = Vt + (size_t)bh * 64 * 1024;
    const unsigned long long* bp = bits + (size_t)b * 1024 * 16;

    // Q as B-operand, loaded direct from global: lane (quad,ln) needs
    // Q[q = w*32 + g*16 + ln][e = kk*32 + quad*8 .. +8] -> one b128 load each.
    short8 qf[2][2];
    #pragma unroll
    for (int g = 0; g < 2; g++)
        #pragma unroll
        for (int kk = 0; kk < 2; kk++)
            qf[g][kk] = as_frag(*(const uint4*)(
                Qp + (size_t)(q0 + w * 32 + g * 16 + ln) * 64 + kk * 32 + quad * 8));

    floatx4 acc_o[2][4];                          // [qg][e-tile]
    #pragma unroll
    for (int g = 0; g < 2; g++)
        #pragma unroll
        for (int i = 0; i < 4; i++) acc_o[g][i] = (floatx4){0.f, 0.f, 0.f, 0.f};
    float lsum[2] = {0.f, 0.f};
    const float scale = 0.03125f;                 // 1/sqrt(1024)
    __hip_bfloat16* Pw = (__hip_bfloat16*)&PsU[w * 256];

    for (int t0 = 0; t0 < 1024; t0 += 64) {
        __syncthreads();                          // prior-iter K/V/Ms reads done
        #pragma unroll
        for (int i = 0; i < 2; i++) {             // K + V tiles: 512 chunks each / 4 waves
            int r = w * 16 + i * 8 + (lane >> 3);
            int kc = (lane & 7) ^ (r & 7);
            char* ldsK = (char*)KsU + (size_t)(w * 128 + i * 64) * 16;
            char* ldsV = (char*)VsU + (size_t)(w * 128 + i * 64) * 16;
            dma16(Kp + (size_t)(t0 + r) * 64 + kc * 8, ldsK);
            dma16(Vp + (size_t)r * 1024 + t0 + kc * 8, ldsV);
        }
        if (tid < 128)
            Ms[tid] = bp[(size_t)(q0 + tid) * 16 + (t0 >> 6)];
        __syncthreads();

        // S^T = K Q^T: K as A (m=t), Q as B (n=q). K-frags shared across q-groups.
        floatx4 st[2][4];
        #pragma unroll
        for (int g = 0; g < 2; g++)
            #pragma unroll
            for (int i = 0; i < 4; i++) st[g][i] = (floatx4){0.f, 0.f, 0.f, 0.f};
        #pragma unroll
        for (int kk = 0; kk < 2; kk++) {
            #pragma unroll
            for (int tt = 0; tt < 4; tt++) {
                short8 kf = as_frag(KsU[swz(tt * 16 + ln, kk * 4 + quad)]);
                st[0][tt] = mfma16(kf, qf[0][kk], st[0][tt]);
                st[1][tt] = mfma16(kf, qf[1][kk], st[1][tt]);
            }
        }

        // P = masked exp; write swizzled chunk layout: row = local q, col = t
        #pragma unroll
        for (int g = 0; g < 2; g++) {
            int qloc = g * 16 + ln;
            unsigned long long mw = Ms[w * 32 + qloc];
            #pragma unroll
            for (int tt = 0; tt < 4; tt++) {
                unsigned mb = (unsigned)(mw >> (tt * 16 + quad * 4)) & 0xFu;
                float pe0 = (mb & 1u) ? 0.f : __expf(st[g][tt][0] * scale);
                float pe1 = (mb & 2u) ? 0.f : __expf(st[g][tt][1] * scale);
                float pe2 = (mb & 4u) ? 0.f : __expf(st[g][tt][2] * scale);
                float pe3 = (mb & 8u) ? 0.f : __expf(st[g][tt][3] * scale);
                lsum[g] += (pe0 + pe1) + (pe2 + pe3);
                int kc = tt * 2 + (quad >> 1);            // logical chunk of col
                int off = qloc * 64 + (kc ^ (qloc & 7)) * 8 + (quad & 1) * 4;
                *(uint2*)(Pw + off) = pack4(pe0, pe1, pe2, pe3);
            }
        }

        // O^T += V^T P^T: V as A (rows e), P as B (swizzled conflict-free read)
        #pragma unroll
        for (int kk = 0; kk < 2; kk++) {
            short8 pf0 = as_frag(PsU[w * 256 + swz(0 * 16 + ln, kk * 4 + quad)]);
            short8 pf1 = as_frag(PsU[w * 256 + swz(1 * 16 + ln, kk * 4 + quad)]);
            #pragma unroll
            for (int et = 0; et < 4; et++) {
                short8 vf = as_frag(VsU[swz(et * 16 + ln, kk * 4 + quad)]);
                acc_o[0][et] = mfma16(vf, pf0, acc_o[0][et]);
                acc_o[1][et] = mfma16(vf, pf1, acc_o[1][et]);
            }
        }
    }

    // reduce l across quads (each quad summed its t-subset)
    #pragma unroll
    for (int g = 0; g < 2; g++) {
        lsum[g] += __shfl_xor(lsum[g], 16, 64);
        lsum[g] += __shfl_xor(lsum[g], 32, 64);
    }

    // O^T C-layout: col=q=ln, row=e=quad*4+r -> 4 consecutive d per lane: 8B stores
    #pragma unroll
    for (int g = 0; g < 2; g++) {
        float inv = 1.f / fmaxf(lsum[g], 1e-20f);
        int s = q0 + w * 32 + g * 16 + ln;
        __hip_bfloat16* crow = ctx + ((size_t)b * 1024 + s) * 1024 + h * 64 + quad * 4;
        #pragma unroll
        for (int et = 0; et < 4; et++) {
            uint2 pk = pack4(acc_o[g][et][0] * inv, acc_o[g][et][1] * inv,
                             acc_o[g][et][2] * inv, acc_o[g][et][3] * inv);
            *(uint2*)(crow + et * 16) = pk;
        }
    }
}

// ---------------------------------------------------------------- out GEMM (DMA)
// 128x128 tiles, 2x2 waves (wave = 64m x 64n); fused dual-mode output write.
__global__ __launch_bounds__(256) void out_gemm_dma(
    const __hip_bfloat16* __restrict__ Cx,   // ctx [8192,1024]
    const __hip_bfloat16* __restrict__ WoT,  // [1024 n][1024 k]
    const __hip_bfloat16* __restrict__ bc,
    const unsigned* __restrict__ Xw,
    void* __restrict__ dout,
    int direct)
{
    __shared__ int s_is32;
    detect_mode(Xw, &s_is32);
    __shared__ uint4 AsU[128 * 8];
    __shared__ uint4 BsU[128 * 8];
    int tid = threadIdx.x, lane = tid & 63, wave = tid >> 6;
    int quad = lane >> 4, ln = lane & 15;
    int mw = wave & 1, nw = wave >> 1;
    int m0 = blockIdx.x * 128;
    int n0 = blockIdx.y * 128;

    floatx4 acc[4][4];
    #pragma unroll
    for (int i = 0; i < 4; i++)
        #pragma unroll
        for (int j = 0; j < 4; j++) acc[i][j] = (floatx4){0.f, 0.f, 0.f, 0.f};

    for (int k0 = 0; k0 < 1024; k0 += 64) {
        #pragma unroll
        for (int i = 0; i < 4; i++) {
            int r = wave * 32 + i * 8 + (lane >> 3);
            int kc = (lane & 7) ^ (r & 7);
            char* ldsA = (char*)AsU + (size_t)(wave * 256 + i * 64) * 16;
            char* ldsB = (char*)BsU + (size_t)(wave * 256 + i * 64) * 16;
            dma16(Cx + (size_t)(m0 + r) * 1024 + k0 + kc * 8, ldsA);
            dma16(WoT + (size_t)(n0 + r) * 1024 + k0 + kc * 8, ldsB);
        }
        __syncthreads();
        #pragma unroll
        for (int kk = 0; kk < 2; kk++) {
            short8 af[4], bf[4];
            #pragma unroll
            for (int mi = 0; mi < 4; mi++)
                af[mi] = as_frag(AsU[swz(mw * 64 + mi * 16 + ln, kk * 4 + quad)]);
            #pragma unroll
            for (int ni = 0; ni < 4; ni++)
                bf[ni] = as_frag(BsU[swz(nw * 64 + ni * 16 + ln, kk * 4 + quad)]);
            #pragma unroll
            for (int mi = 0; mi < 4; mi++)
                #pragma unroll
                for (int ni = 0; ni < 4; ni++)
                    acc[mi][ni] = mfma16(af[mi], bf[ni], acc[mi][ni]);
        }
        __syncthreads();
    }

    const __hip_bfloat16* bo = bc + 3 * 1024;
    #pragma unroll
    for (int ni = 0; ni < 4; ni++) {
        int n = n0 + nw * 64 + ni * 16 + ln;
        float bval = __bfloat162float(bo[n]);
        #pragma unroll
        for (int mi = 0; mi < 4; mi++) {
            #pragma unroll
            for (int r = 0; r < 4; r++) {
                int m = m0 + mw * 64 + mi * 16 + quad * 4 + r;
                float v = acc[mi][ni][r] + bval;
                if (direct && s_is32) ((float*)dout)[(size_t)m * 1024 + n] = v;
                else ((__hip_bfloat16*)dout)[(size_t)m * 1024 + n] = __float2bfloat16(v);
            }
        }
    }
}

// ---------------------------------------------------------------- emit (fallback)
__global__ __launch_bounds__(256) void emit_out(
    const __hip_bfloat16* __restrict__ Fo, const unsigned* __restrict__ Xw,
    void* __restrict__ dout)
{
    __shared__ int s_is32;
    detect_mode(Xw, &s_is32);
    size_t g = (size_t)blockIdx.x * 256 + threadIdx.x;
    uint4 u = *(const uint4*)(Fo + g * 8);
    if (s_is32) {
        short8 s = __builtin_bit_cast(short8, u);
        float4 f0, f1;
        f0.x = b2f(s[0]); f0.y = b2f(s[1]); f0.z = b2f(s[2]); f0.w = b2f(s[3]);
        f1.x = b2f(s[4]); f1.y = b2f(s[5]); f1.z = b2f(s[6]); f1.w = b2f(s[7]);
        *(float4*)((float*)dout + g * 8) = f0;
        *(float4*)((float*)dout + g * 8 + 4) = f1;
    } else {
        *(uint4*)((__hip_bfloat16*)dout + g * 8) = u;
    }
}

// ---------------------------------------------------------------- launch
extern "C" void kernel_launch(void* const* d_in, const int* in_sizes, int n_in,
                              void* d_out, int out_size, void* d_ws, size_t ws_size,
                              hipStream_t stream) {
    const void* X  = d_in[0];
    const void* mk = d_in[1];
    const void* Wq = d_in[2];
    const void* bq = d_in[3];
    const void* Wk = d_in[4];
    const void* bk = d_in[5];
    const void* Wv = d_in[6];
    const void* bv = d_in[7];
    const void* Wo = d_in[8];
    const void* bo = d_in[9];
    const unsigned* Xw = (const unsigned*)X;

    char* ws = (char*)d_ws;
    __hip_bfloat16*     WT   = (__hip_bfloat16*)(ws);                        // [0, 6 MB)
    __hip_bfloat16*     WoT  = (__hip_bfloat16*)(ws + ((size_t)6 << 20));    // [6, 8 MB)
    unsigned long long* bits = (unsigned long long*)(ws + ((size_t)8 << 20));// [8, 9 MB)
    __hip_bfloat16*     bc   = (__hip_bfloat16*)(ws + ((size_t)9 << 20));    // [9, +8KB)
    __hip_bfloat16*     Xb   = (__hip_bfloat16*)(ws + ((size_t)10 << 20));   // [10, 26 MB)
    __hip_bfloat16*     Qb   = (__hip_bfloat16*)(ws + ((size_t)26 << 20));   // [26, 42 MB)
    __hip_bfloat16*     Kb   = (__hip_bfloat16*)(ws + ((size_t)42 << 20));   // [42, 58 MB)
    __hip_bfloat16*     Vtb  = (__hip_bfloat16*)(ws + ((size_t)58 << 20));   // [58, 74 MB)

    bool bigws = ws_size >= ((size_t)74 << 20);

    hipLaunchKernelGGL(prep_all, dim3(3585), dim3(256), 0, stream,
                       Wq, Wk, Wv, Wo, bq, bk, bv, bo, mk, X,
                       WT, WoT, bc, bits, Xb, bigws ? 1 : 0);

    if (bigws) {
        __hip_bfloat16* Cx = Xb;   // ctx reuses Xb (dead after qkv)
        hipLaunchKernelGGL(qkv_gemm_dma, dim3(32, 24), dim3(256), 0, stream,
                           Xb, WT, bc, Qb, Kb, Vtb);
        hipLaunchKernelGGL(attn, dim3(128, 8), dim3(256), 0, stream,
                           Qb, Kb, Vtb, bits, Cx);
        hipLaunchKernelGGL(out_gemm_dma, dim3(64, 8), dim3(256), 0, stream,
                           Cx, WoT, bc, Xw, d_out, 1);
    } else {
        __hip_bfloat16* Cx = (__hip_bfloat16*)d_out;   // ctx scratch in d_out
        __hip_bfloat16* Fo = Qb;                        // final bf16 over dead Q
        hipLaunchKernelGGL(qkv_gemm2, dim3(64, 24), dim3(256), 0, stream,
                           X, WT, bc, Qb, Kb, Vtb);
        hipLaunchKernelGGL(attn, dim3(128, 8), dim3(256), 0, stream,
                           Qb, Kb, Vtb, bits, Cx);
        hipLaunchKernelGGL(out_gemm_dma, dim3(64, 8), dim3(256), 0, stream,
                           Cx, WoT, bc, Xw, (void*)Fo, 0);
        hipLaunchKernelGGL(emit_out, dim3(4096), dim3(256), 0, stream,
                           Fo, Xw, d_out);
    }
}